// Round 5
// baseline (385.855 us; speedup 1.0000x reference)
//
#include <hip/hip_runtime.h>
#include <hip/hip_bf16.h>

// MultiHeadAttention: B=4 S=2048 E=1024 H=16 Dk=64
// fp32 in/out, bf16 intermediates.
#define B_  4
#define S_  2048
#define E_  1024
#define H_  16
#define DK_ 64
#define CSC 0.18033688011112042f  // log2(e)/sqrt(Dk), folded into bf16 Wq

using bf16   = __bf16;
using bf16x8 = __attribute__((ext_vector_type(8))) __bf16;
using f32x4  = __attribute__((ext_vector_type(4))) float;

__device__ __forceinline__ f32x4 mfma16(bf16x8 a, bf16x8 b, f32x4 c) {
    return __builtin_amdgcn_mfma_f32_16x16x32_bf16(a, b, c, 0, 0, 0);
}

__device__ __forceinline__ bf16x8 cvt8(float4 a, float4 b) {
    bf16x8 r;
    r[0] = (bf16)a.x; r[1] = (bf16)a.y; r[2] = (bf16)a.z; r[3] = (bf16)a.w;
    r[4] = (bf16)b.x; r[5] = (bf16)b.y; r[6] = (bf16)b.z; r[7] = (bf16)b.w;
    return r;
}

// async global->LDS, 16B/lane; LDS dest = wave-uniform base + lane*16.
__device__ __forceinline__ void gl16(const void* g, void* l) {
    __builtin_amdgcn_global_load_lds(
        (const __attribute__((address_space(1))) void*)g,
        (__attribute__((address_space(3))) void*)l, 16, 0, 0);
}

#define SBAR()  __builtin_amdgcn_s_barrier()
// rule #18: sched_barrier(0) after inline-asm waits so MFMA can't hoist above.
#define WV4()  { asm volatile("s_waitcnt vmcnt(4)" ::: "memory");   \
                 __builtin_amdgcn_sched_barrier(0); }
#define WL0()  { asm volatile("s_waitcnt lgkmcnt(0)" ::: "memory"); \
                 __builtin_amdgcn_sched_barrier(0); }

// ---------------------------------------------------------------------------
// fp32 -> bf16 streaming converts.
// ---------------------------------------------------------------------------
__global__ __launch_bounds__(256) void cvt_pair(const float* __restrict__ a,
                                                const float* __restrict__ b,
                                                bf16* __restrict__ da,
                                                bf16* __restrict__ db) {
    const float* s = blockIdx.y ? b : a;
    bf16* d = blockIdx.y ? db : da;
    const size_t i = (size_t)blockIdx.x * 256 + threadIdx.x;
    const float4 u = ((const float4*)s)[i * 2];
    const float4 v = ((const float4*)s)[i * 2 + 1];
    ((bf16x8*)d)[i] = cvt8(u, v);
}

__global__ __launch_bounds__(256) void cvtw3(const float* __restrict__ a,
                                             const float* __restrict__ b,
                                             const float* __restrict__ c,
                                             bf16* __restrict__ d, float s0) {
    const int y = blockIdx.y;
    const float* s = y == 0 ? a : y == 1 ? b : c;
    const float sc = y == 0 ? s0 : 1.f;
    const size_t i = (size_t)blockIdx.x * 256 + threadIdx.x;
    float4 u = ((const float4*)s)[i * 2];
    float4 v = ((const float4*)s)[i * 2 + 1];
    u.x *= sc; u.y *= sc; u.z *= sc; u.w *= sc;
    v.x *= sc; v.y *= sc; v.z *= sc; v.w *= sc;
    ((bf16x8*)(d + (size_t)y * E_ * E_))[i] = cvt8(u, v);
}

// ---------------------------------------------------------------------------
// 256x256 8-wave GEMM, 4-phase/K-tile counted-vmcnt schedule (T2+T3+T4+T5).
// C = A @ W^T, A,W bf16 row-major [.,1024]. BK=64, 16 K-tiles.
// LDS 128KB: buf{0,1} x (A[256][64] | B[256][64]), rows 128B, XOR-chunk
// swizzle chunk' = chunk ^ (row&7) carried by the gl16 SOURCE address
// (linear LDS dest) and the ds_read address (both-sides rule).
// Staging: per phase one half-tile (2 gl16/thread). Half split matches
// consumption: A-alpha = rows {0-63,128-191} (mh0 of both wm), etc.
// Ledger (stage order Aa,Ba,Bb,Ab per iter; reads p0:Aa+Ba p1:Bb p2:Ab p3:Ba):
// vmcnt(4) at p0/p1/p3 proves every deadline with >=2 phases in flight;
// never drains to 0 in the loop.
// MODE 0: fused QKV epilogue scatter (sel via selbase+blockIdx.y>>2);
// MODE 1: fp32 linear out.
// ---------------------------------------------------------------------------
template <int MODE>
__global__ __launch_bounds__(512, 2) void gemm8(
    const bf16* __restrict__ Aq, const bf16* __restrict__ Ak,
    const bf16* __restrict__ Av, const bf16* __restrict__ Wb,
    bf16* __restrict__ qws, bf16* __restrict__ kws, bf16* __restrict__ vtws,
    float* __restrict__ fout, int selbase) {
    extern __shared__ __align__(16) char sm[];

    const int t = threadIdx.x;
    const int lane = t & 63, w = t >> 6;
    const int wm = w >> 2, wn = w & 3;
    const int quad = lane >> 4, l16 = lane & 15;

    int sel, gn;
    if (MODE == 0) {
        sel = selbase + (blockIdx.y >> 2);
        gn = (blockIdx.y & 3) * 256;
    } else {
        sel = 0;
        gn = blockIdx.y * 256;
    }
    const int gm = blockIdx.x * 256;

    const bf16* A = (MODE == 1) ? Aq : (sel == 0 ? Aq : sel == 1 ? Ak : Av);
    const bf16* W = (MODE == 1) ? Wb : Wb + (size_t)sel * E_ * E_;

    // ---- staging geometry -------------------------------------------------
    const int lr = lane >> 3;             // sub-row in 8-row slot
    const int scw = (lane & 7) ^ lr;      // pre-swizzled source chunk
    const int s0 = w * 2, s1 = s0 + 1;
    const int arow0 = (s0 >> 3) * 128 + (s0 & 7) * 8;   // A slot rows (alpha)
    const int arow1 = (s1 >> 3) * 128 + (s1 & 7) * 8;
    const int brow0 = (s0 >> 2) * 64 + (s0 & 3) * 8;    // B slot rows (alpha)
    const int brow1 = (s1 >> 2) * 64 + (s1 & 3) * 8;

    // per-lane global sources (byte ptrs); advance +nkt*128 per stage
    const char* gAa0 = (const char*)(A + (size_t)(gm + arow0 + lr) * E_) + scw * 16;
    const char* gAa1 = (const char*)(A + (size_t)(gm + arow1 + lr) * E_) + scw * 16;
    const char* gAb0 = gAa0 + (size_t)64 * E_ * 2;
    const char* gAb1 = gAa1 + (size_t)64 * E_ * 2;
    const char* gBa0 = (const char*)(W + (size_t)(gn + brow0 + lr) * E_) + scw * 16;
    const char* gBa1 = (const char*)(W + (size_t)(gn + brow1 + lr) * E_) + scw * 16;
    const char* gBb0 = gBa0 + (size_t)32 * E_ * 2;
    const char* gBb1 = gBa1 + (size_t)32 * E_ * 2;

#define STG_Aa(nb, kb) { gl16(gAa0 + (kb), sm + (nb) + arow0 * 128);              \
                         gl16(gAa1 + (kb), sm + (nb) + arow1 * 128); }
#define STG_Ab(nb, kb) { gl16(gAb0 + (kb), sm + (nb) + (arow0 + 64) * 128);       \
                         gl16(gAb1 + (kb), sm + (nb) + (arow1 + 64) * 128); }
#define STG_Ba(nb, kb) { gl16(gBa0 + (kb), sm + (nb) + 32768 + brow0 * 128);      \
                         gl16(gBa1 + (kb), sm + (nb) + 32768 + brow1 * 128); }
#define STG_Bb(nb, kb) { gl16(gBb0 + (kb), sm + (nb) + 32768 + (brow0+32) * 128); \
                         gl16(gBb1 + (kb), sm + (nb) + 32768 + (brow1+32) * 128); }

    // ---- fragment-read geometry (swizzled) --------------------------------
    const int cK0 = ((0 * 4 + quad) ^ (l16 & 7)) * 16;  // kh=0 chunk byte
    const int cK1 = ((1 * 4 + quad) ^ (l16 & 7)) * 16;  // kh=1

    f32x4 acc[8][4];
#pragma unroll
    for (int i = 0; i < 8; ++i)
#pragma unroll
        for (int j = 0; j < 4; ++j) acc[i][j] = f32x4{0.f, 0.f, 0.f, 0.f};

    bf16x8 Af[4][2], Bf[2][2];

#define LDA(cb, MH)                                                            \
    _Pragma("unroll") for (int ml = 0; ml < 4; ++ml) {                         \
        const int rb = (wm * 128 + (MH) * 64 + ml * 16 + l16) * 128;           \
        Af[ml][0] = *(const bf16x8*)(sm + (cb) + rb + cK0);                    \
        Af[ml][1] = *(const bf16x8*)(sm + (cb) + rb + cK1);                    \
    }
#define LDB(cb, NH)                                                            \
    _Pragma("unroll") for (int nl = 0; nl < 2; ++nl) {                         \
        const int rb = (wn * 64 + (NH) * 32 + nl * 16 + l16) * 128;            \
        Bf[nl][0] = *(const bf16x8*)(sm + (cb) + 32768 + rb + cK0);            \
        Bf[nl][1] = *(const bf16x8*)(sm + (cb) + 32768 + rb + cK1);            \
    }
#define MFMAQ(MH, NH)                                                          \
    __builtin_amdgcn_s_setprio(1);                                             \
    _Pragma("unroll") for (int ml = 0; ml < 4; ++ml)                           \
    _Pragma("unroll") for (int nl = 0; nl < 2; ++nl) {                         \
        acc[(MH)*4+ml][(NH)*2+nl] =                                            \
            mfma16(Af[ml][0], Bf[nl][0], acc[(MH)*4+ml][(NH)*2+nl]);           \
        acc[(MH)*4+ml][(NH)*2+nl] =                                            \
            mfma16(Af[ml][1], Bf[nl][1], acc[(MH)*4+ml][(NH)*2+nl]);           \
    }                                                                          \
    __builtin_amdgcn_s_setprio(0);

    // ---- prologue: stage K-tile 0 into buf0 -------------------------------
    STG_Aa(0, 0); STG_Ba(0, 0); STG_Bb(0, 0); STG_Ab(0, 0);
    WV4();   // Aa0,Ba0 landed (allow Bb0,Ab0 in flight)
    SBAR();

    // ---- main loop: 16 K-tiles, 4 phases each -----------------------------
    for (int kt = 0; kt < 16; ++kt) {
        const size_t cb = (size_t)(kt & 1) * 65536;
        const size_t nb = cb ^ 65536;
        const size_t kb = (size_t)(kt + 1 < 16 ? kt + 1 : 15) * 128;

        // p0: quadrant (mh0, nh0)
        LDA(cb, 0); LDB(cb, 0);
        STG_Aa(nb, kb);
        WV4(); SBAR(); WL0();
        MFMAQ(0, 0);
        SBAR();

        // p1: (mh0, nh1) — reuse A
        LDB(cb, 1);
        STG_Ba(nb, kb);
        WV4(); SBAR(); WL0();
        MFMAQ(0, 1);
        SBAR();

        // p2: (mh1, nh1) — reuse B
        LDA(cb, 1);
        STG_Bb(nb, kb);
        SBAR(); WL0();
        MFMAQ(1, 1);
        SBAR();

        // p3: (mh1, nh0)
        LDB(cb, 0);
        STG_Ab(nb, kb);
        WV4(); SBAR(); WL0();
        MFMAQ(1, 0);
        SBAR();
    }

    // ---- epilogue ---------------------------------------------------------
#pragma unroll
    for (int mf = 0; mf < 8; ++mf)
#pragma unroll
        for (int nf = 0; nf < 4; ++nf) {
            const int col = gn + wn * 64 + nf * 16 + l16;
            const int row0 = gm + wm * 128 + mf * 16 + quad * 4;
            if (MODE == 1) {
#pragma unroll
                for (int r = 0; r < 4; ++r)
                    fout[(size_t)(row0 + r) * E_ + col] = acc[mf][nf][r];
            } else {
                const int h = col >> 6, d = col & (DK_ - 1);
#pragma unroll
                for (int r = 0; r < 4; ++r) {
                    const int i = row0 + r;
                    const int bb = i >> 11, s = i & (S_ - 1);
                    const float v = acc[mf][nf][r];
                    if (sel == 2)
                        vtws[(((size_t)(bb * H_ + h)) * DK_ + d) * S_ + s] = (bf16)v;
                    else if (sel == 1)
                        kws[(((size_t)(bb * H_ + h)) * S_ + s) * DK_ + d] = (bf16)v;
                    else
                        qws[(((size_t)(bb * H_ + h)) * S_ + s) * DK_ + d] = (bf16)v;
                }
            }
        }
#undef STG_Aa
#undef STG_Ab
#undef STG_Ba
#undef STG_Bb
#undef LDA
#undef LDB
#undef MFMAQ
}

// ---------------------------------------------------------------------------
// Flash attention (unchanged from round 4; verified).
// ---------------------------------------------------------------------------
#define PSTR 72
__global__ __launch_bounds__(256) void attn4(const bf16* __restrict__ q,
                                             const bf16* __restrict__ k,
                                             const bf16* __restrict__ vt,
                                             bf16* __restrict__ ctx) {
    __shared__ __align__(16) bf16 sK[64 * 64];
    __shared__ __align__(16) bf16 sV[64 * 64];
    __shared__ __align__(16) bf16 plds[4][32 * PSTR];

    const int t = threadIdx.x;
    const int lane = t & 63, wave = t >> 6;
    const int quad = lane >> 4, l16 = lane & 15;
    const int qb = (blockIdx.x * 4 + wave) * 32;
    const int bh = blockIdx.y;
    const size_t base  = (size_t)bh * S_ * DK_;
    const size_t baseT = (size_t)bh * DK_ * S_;
    bf16* pw = &plds[wave][0];

    const int srow = t >> 2, sc4 = (t & 3) * 16;
    const int cb = (t & 3) * 2, swr = srow & 7;
    const bf16* gK = k + base + (size_t)srow * DK_ + sc4;
    const bf16* gV = vt + baseT + (size_t)srow * S_ + sc4;
    char* wK0 = (char*)sK + srow * 128 + ((cb ^ swr) * 16);
    char* wK1 = (char*)sK + srow * 128 + (((cb + 1) ^ swr) * 16);
    char* wV0 = (char*)sV + srow * 128 + ((cb ^ swr) * 16);
    char* wV1 = (char*)sV + srow * 128 + (((cb + 1) ^ swr) * 16);

    bf16x8 rk[2], rv[2];
    rk[0] = *(const bf16x8*)(gK);
    rk[1] = *(const bf16x8*)(gK + 8);
    rv[0] = *(const bf16x8*)(gV);
    rv[1] = *(const bf16x8*)(gV + 8);

    bf16x8 aQ[2][2];
#pragma unroll
    for (int t2 = 0; t2 < 2; ++t2) {
        const bf16* qp = q + base + (size_t)(qb + t2 * 16 + l16) * DK_ + quad * 8;
        aQ[t2][0] = *(const bf16x8*)(qp);
        aQ[t2][1] = *(const bf16x8*)(qp + 32);
    }

    f32x4 acc[2][4];
    float l_i[2][4];
#pragma unroll
    for (int t2 = 0; t2 < 2; ++t2)
#pragma unroll
        for (int nb = 0; nb < 4; ++nb) {
            acc[t2][nb] = f32x4{0.f, 0.f, 0.f, 0.f};
            l_i[t2][nb] = 0.f;
        }

    for (int kt = 0; kt < S_ / 64; ++kt) {
        __syncthreads();
        *(bf16x8*)wK0 = rk[0];
        *(bf16x8*)wK1 = rk[1];
        *(bf16x8*)wV0 = rv[0];
        *(bf16x8*)wV1 = rv[1];
        __syncthreads();
        if (kt + 1 < S_ / 64) {
            const bf16* nK = gK + (size_t)(kt + 1) * 64 * DK_;
            const bf16* nV = gV + (size_t)(kt + 1) * 64;
            rk[0] = *(const bf16x8*)(nK);
            rk[1] = *(const bf16x8*)(nK + 8);
            rv[0] = *(const bf16x8*)(nV);
            rv[1] = *(const bf16x8*)(nV + 8);
        }

        f32x4 sc[2][4];
#pragma unroll
        for (int kb = 0; kb < 4; ++kb) {
            const int r = kb * 16 + l16, sw = r & 7;
            const bf16x8 b0 =
                *(const bf16x8*)((const char*)sK + r * 128 + ((quad ^ sw) * 16));
            const bf16x8 b1 = *(const bf16x8*)((const char*)sK + r * 128 +
                                               (((quad + 4) ^ sw) * 16));
#pragma unroll
            for (int t2 = 0; t2 < 2; ++t2) {
                f32x4 z = f32x4{0.f, 0.f, 0.f, 0.f};
                z = mfma16(aQ[t2][0], b0, z);
                sc[t2][kb] = mfma16(aQ[t2][1], b1, z);
            }
        }

#pragma unroll
        for (int t2 = 0; t2 < 2; ++t2)
#pragma unroll
            for (int r = 0; r < 4; ++r) {
                const int prow = (t2 * 16 + quad * 4 + r) * PSTR;
#pragma unroll
                for (int kb = 0; kb < 4; ++kb) {
                    const float p = __builtin_amdgcn_exp2f(sc[t2][kb][r]);
                    l_i[t2][r] += p;
                    pw[prow + kb * 16 + l16] = (bf16)p;
                }
            }

        bf16x8 aP[2][2];
#pragma unroll
        for (int t2 = 0; t2 < 2; ++t2) {
            aP[t2][0] = *(const bf16x8*)(pw + (t2 * 16 + l16) * PSTR + quad * 8);
            aP[t2][1] = *(const bf16x8*)(pw + (t2 * 16 + l16) * PSTR + 32 + quad * 8);
        }

#pragma unroll
        for (int nb = 0; nb < 4; ++nb) {
            const int r = nb * 16 + l16, sw = r & 7;
            const bf16x8 b0 =
                *(const bf16x8*)((const char*)sV + r * 128 + ((quad ^ sw) * 16));
            const bf16x8 b1 = *(const bf16x8*)((const char*)sV + r * 128 +
                                               (((quad + 4) ^ sw) * 16));
#pragma unroll
            for (int t2 = 0; t2 < 2; ++t2) {
                acc[t2][nb] = mfma16(aP[t2][0], b0, acc[t2][nb]);
                acc[t2][nb] = mfma16(aP[t2][1], b1, acc[t2][nb]);
            }
        }
    }

#pragma unroll
    for (int t2 = 0; t2 < 2; ++t2)
#pragma unroll
        for (int r = 0; r < 4; ++r) {
            float x = l_i[t2][r];
            x += __shfl_xor(x, 1);
            x += __shfl_xor(x, 2);
            x += __shfl_xor(x, 4);
            x += __shfl_xor(x, 8);
            l_i[t2][r] = 1.f / x;
        }

    const int b = bh >> 4, h = bh & (H_ - 1);
#pragma unroll
    for (int t2 = 0; t2 < 2; ++t2)
#pragma unroll
        for (int nb = 0; nb < 4; ++nb)
#pragma unroll
            for (int r = 0; r < 4; ++r) {
                const int s = qb + t2 * 16 + quad * 4 + r;
                const size_t idx =
                    ((size_t)(b * S_ + s)) * E_ + h * DK_ + nb * 16 + l16;
                ctx[idx] = (bf16)(acc[t2][nb][r] * l_i[t2][r]);
            }
}

// ---------------------------------------------------------------------------
extern "C" void kernel_launch(void* const* d_in, const int* in_sizes, int n_in,
                              void* d_out, int out_size, void* d_ws,
                              size_t ws_size, hipStream_t stream) {
    const float* Q  = (const float*)d_in[0];
    const float* K  = (const float*)d_in[1];
    const float* V  = (const float*)d_in[2];
    // d_in[3] = mask (unused)
    const float* Wq = (const float*)d_in[4];
    const float* Wk = (const float*)d_in[5];
    const float* Wv = (const float*)d_in[6];
    const float* Wo = (const float*)d_in[7];
    float* out = (float*)d_out;

    const size_t NTOK = (size_t)B_ * S_ * E_;  // 8,388,608
    bf16* qws  = (bf16*)d_ws;
    bf16* kws  = qws + NTOK;
    bf16* vtws = kws + NTOK;
    bf16* cws  = vtws + NTOK;  // 67.1 MB ws total (unchanged, proven fits)

    // dead-phase aliases:
    //  Wq/Wk/Wv bf16 -> cws region (ctx not written until attn4)
    //  Wo bf16       -> qws region (q dead after attn4)
    //  Qb/Kb/Vb bf16 -> d_out used as scratch (out written only by gemm8<1>;
    //                   Qb+Kb = 33.5 MB = out_size exactly; Vb overlays Qb
    //                   after the Q/K GEMM consumed it)
    bf16* wqkvb = cws;
    bf16* wob   = qws;
    bf16* Qb = (bf16*)d_out;
    bf16* Kb = Qb + NTOK;
    bf16* Vb = Qb;

    cvt_pair<<<dim3(4096, 2), 256, 0, stream>>>(Q, K, Qb, Kb);
    cvtw3<<<dim3(512, 3), 256, 0, stream>>>(Wq, Wk, Wv, wqkvb, CSC);

    // Q & K projections (sel 0,1): 256 blocks = 1/CU
    gemm8<0><<<dim3(32, 8), 512, 131072, stream>>>(
        Qb, Kb, Vb, wqkvb, qws, kws, vtws, nullptr, 0);

    cvt_pair<<<dim3(4096, 1), 256, 0, stream>>>(V, V, Vb, Vb);

    // V projection (sel 2)
    gemm8<0><<<dim3(32, 4), 512, 131072, stream>>>(
        Qb, Kb, Vb, wqkvb, qws, kws, vtws, nullptr, 2);

    attn4<<<dim3(S_ / 128, B_ * H_), 256, 0, stream>>>(qws, kws, vtws, cws);

    cvtw3<<<dim3(512, 1), 256, 0, stream>>>(Wo, Wo, Wo, wob, 1.f);

    gemm8<1><<<dim3(32, 4), 512, 131072, stream>>>(
        cws, cws, cws, wob, nullptr, nullptr, nullptr, out, 0);
}

// Round 6
// 384.410 us; speedup vs baseline: 1.0038x; 1.0038x over previous
//
#include <hip/hip_runtime.h>
#include <hip/hip_bf16.h>

// MultiHeadAttention: B=4 S=2048 E=1024 H=16 Dk=64
// fp32 in/out, bf16 intermediates.
#define B_  4
#define S_  2048
#define E_  1024
#define H_  16
#define DK_ 64
#define CSC 0.18033688011112042f  // log2(e)/sqrt(Dk), folded into bf16 Wq

using bf16   = __bf16;
using bf16x8 = __attribute__((ext_vector_type(8))) __bf16;
using f32x4  = __attribute__((ext_vector_type(4))) float;

__device__ __forceinline__ f32x4 mfma16(bf16x8 a, bf16x8 b, f32x4 c) {
    return __builtin_amdgcn_mfma_f32_16x16x32_bf16(a, b, c, 0, 0, 0);
}

__device__ __forceinline__ bf16x8 cvt8(float4 a, float4 b) {
    bf16x8 r;
    r[0] = (bf16)a.x; r[1] = (bf16)a.y; r[2] = (bf16)a.z; r[3] = (bf16)a.w;
    r[4] = (bf16)b.x; r[5] = (bf16)b.y; r[6] = (bf16)b.z; r[7] = (bf16)b.w;
    return r;
}

// async global->LDS, 16B/lane; LDS dest = wave-uniform base + lane*16.
__device__ __forceinline__ void gl16(const void* g, void* l) {
    __builtin_amdgcn_global_load_lds(
        (const __attribute__((address_space(1))) void*)g,
        (__attribute__((address_space(3))) void*)l, 16, 0, 0);
}

#define SBAR() __builtin_amdgcn_s_barrier()
// rule #18: sched_barrier(0) after inline-asm waits so dependent ops can't hoist.
#define WV6() { asm volatile("s_waitcnt vmcnt(6)" ::: "memory");   \
                __builtin_amdgcn_sched_barrier(0); }
#define WV3() { asm volatile("s_waitcnt vmcnt(3)" ::: "memory");   \
                __builtin_amdgcn_sched_barrier(0); }
#define WV0() { asm volatile("s_waitcnt vmcnt(0)" ::: "memory");   \
                __builtin_amdgcn_sched_barrier(0); }
#define WL0() { asm volatile("s_waitcnt lgkmcnt(0)" ::: "memory"); \
                __builtin_amdgcn_sched_barrier(0); }

// ---------------------------------------------------------------------------
// fp32 -> bf16 streaming converts.
// ---------------------------------------------------------------------------
__global__ __launch_bounds__(256) void cvt_pair(const float* __restrict__ a,
                                                const float* __restrict__ b,
                                                bf16* __restrict__ da,
                                                bf16* __restrict__ db) {
    const float* s = blockIdx.y ? b : a;
    bf16* d = blockIdx.y ? db : da;
    const size_t i = (size_t)blockIdx.x * 256 + threadIdx.x;
    const float4 u = ((const float4*)s)[i * 2];
    const float4 v = ((const float4*)s)[i * 2 + 1];
    ((bf16x8*)d)[i] = cvt8(u, v);
}

__global__ __launch_bounds__(256) void cvtw3(const float* __restrict__ a,
                                             const float* __restrict__ b,
                                             const float* __restrict__ c,
                                             bf16* __restrict__ d, float s0) {
    const int y = blockIdx.y;
    const float* s = y == 0 ? a : y == 1 ? b : c;
    const float sc = y == 0 ? s0 : 1.f;
    const size_t i = (size_t)blockIdx.x * 256 + threadIdx.x;
    float4 u = ((const float4*)s)[i * 2];
    float4 v = ((const float4*)s)[i * 2 + 1];
    u.x *= sc; u.y *= sc; u.z *= sc; u.w *= sc;
    v.x *= sc; v.y *= sc; v.z *= sc; v.w *= sc;
    ((bf16x8*)(d + (size_t)y * E_ * E_))[i] = cvt8(u, v);
}

// ---------------------------------------------------------------------------
// 128x256 8-wave GEMM on a 4-slab LDS ring (deep counted-vmcnt pipeline).
// C = A @ W^T, A,W bf16 row-major [.,1024]. Slab = K-step 32:
//   { A[128][32] 8KB | B[256][32] 16KB } = 24KB, ring of 4 = 96KB LDS.
// Stage slab s+3 while computing s (lead ~3 slab-times ~ HBM latency).
// ONE s_barrier + ONE counted vmcnt per slab, never 0 in the main loop:
//   at slab s entry, un-landed loads = stages for s+1,s+2 = 6 -> vmcnt(6)
//   guarantees slab s landed; barrier makes it collective (each wave's
//   lgkmcnt(0) drains its reads before the barrier, so the buffer written
//   by STG(s+3) -- buf (s-1)%4 -- has no readers). Epilogue waits 6/3/0.
// Swizzle: 64B rows, chunk' = chunk ^ ((row>>1)&3), carried by the gl16
// SOURCE address (linear LDS dest) and the ds_read address (both-sides).
// Round-4 measured this exact layout at ZERO bank conflicts.
// Wave tile 64x64 (2M x 4N), acc[4][4] (~110 VGPR; (512,2) cap 256, no spill).
// MODE 0: QKV epilogue scatter (sel = selbase + blockIdx.y>>2);
// MODE 1: fp32 linear out.
// ---------------------------------------------------------------------------
template <int MODE>
__global__ __launch_bounds__(512, 2) void gemmr(
    const bf16* __restrict__ Aq, const bf16* __restrict__ Ak,
    const bf16* __restrict__ Av, const bf16* __restrict__ Wb,
    bf16* __restrict__ qws, bf16* __restrict__ kws, bf16* __restrict__ vtws,
    float* __restrict__ fout, int selbase) {
    __shared__ __align__(16) char sm[4 * 24576];  // 96 KB

    const int t = threadIdx.x;
    const int lane = t & 63, w = t >> 6;
    const int wm = w >> 2, wn = w & 3;  // 2M x 4N
    const int quad = lane >> 4, l16 = lane & 15;

    int sel, gn;
    if (MODE == 0) {
        sel = selbase + (blockIdx.y >> 2);
        gn = (blockIdx.y & 3) * 256;
    } else {
        sel = 0;
        gn = blockIdx.y * 256;
    }
    const int gm = blockIdx.x * 128;

    const bf16* A = (MODE == 1) ? Aq : (sel == 0 ? Aq : sel == 1 ? Ak : Av);
    const bf16* W = (MODE == 1) ? Wb : Wb + (size_t)sel * E_ * E_;

    // ---- staging geometry: lane covers row l>>2, chunk l&3 (pre-swizzled)
    const int srow = lane >> 2;
    const int scw  = (lane & 3) ^ ((lane >> 3) & 3);  // ((row>>1)&3) == (l>>3)&3
    const char* gA  = (const char*)(A + (size_t)(gm + w * 16 + srow) * E_) + scw * 16;
    const char* gB0 = (const char*)(W + (size_t)(gn + w * 32 + srow) * E_) + scw * 16;
    const char* gB1 = gB0 + (size_t)16 * E_ * 2;

#define STG(s) {                                                       \
        const int _b = ((s) & 3) * 24576;                              \
        const size_t _k = (size_t)(s) * 64; /* 32 bf16 = 64B */        \
        gl16(gA + _k, sm + _b + w * 1024);                             \
        gl16(gB0 + _k, sm + _b + 8192 + w * 2048);                     \
        gl16(gB1 + _k, sm + _b + 8192 + w * 2048 + 1024);              \
    }

    bf16x8 Af[4], Bf[4];
#define LDFRAGS(s) {                                                   \
        const int _b = ((s) & 3) * 24576;                              \
        _Pragma("unroll") for (int ms = 0; ms < 4; ++ms) {             \
            const int r = wm * 64 + ms * 16 + l16;                     \
            Af[ms] = *(const bf16x8*)(sm + _b + r * 64 +               \
                                      ((quad ^ ((r >> 1) & 3)) * 16)); \
        }                                                              \
        _Pragma("unroll") for (int ns = 0; ns < 4; ++ns) {             \
            const int r = wn * 64 + ns * 16 + l16;                     \
            Bf[ns] = *(const bf16x8*)(sm + _b + 8192 + r * 64 +        \
                                      ((quad ^ ((r >> 1) & 3)) * 16)); \
        }                                                              \
    }

#define MFMACL() {                                                     \
        __builtin_amdgcn_s_setprio(1);                                 \
        _Pragma("unroll") for (int ms = 0; ms < 4; ++ms)               \
        _Pragma("unroll") for (int ns = 0; ns < 4; ++ns)               \
            acc[ms][ns] = mfma16(Af[ms], Bf[ns], acc[ms][ns]);         \
        __builtin_amdgcn_s_setprio(0);                                 \
    }

    f32x4 acc[4][4];
#pragma unroll
    for (int i = 0; i < 4; ++i)
#pragma unroll
        for (int j = 0; j < 4; ++j) acc[i][j] = f32x4{0.f, 0.f, 0.f, 0.f};

    // ---- prologue: stage slabs 0,1,2 (9 loads in flight)
    STG(0); STG(1); STG(2);

    // ---- main loop: slabs 0..28, stage s+3, one barrier + one vmcnt(6) each
    for (int s = 0; s < 29; ++s) {
        WV6();          // all but stages for s+1,s+2 landed -> slab s in LDS
        SBAR();         // collective; also closes last slab's reads
        STG(s + 3);     // into buf (s-1)%4 -- no readers (see header)
        LDFRAGS(s);
        WL0();          // own ds_reads done (also orders before next SBAR)
        MFMACL();
    }
    // ---- epilogue slabs 29,30,31: waits 6 -> 3 -> 0, no staging
    WV6(); SBAR(); LDFRAGS(29); WL0(); MFMACL();
    WV3(); SBAR(); LDFRAGS(30); WL0(); MFMACL();
    WV0(); SBAR(); LDFRAGS(31); WL0(); MFMACL();

    // ---- epilogue: C/D col = lane&15, row = quad*4 + reg [HW-verified]
#pragma unroll
    for (int ms = 0; ms < 4; ++ms)
#pragma unroll
        for (int ns = 0; ns < 4; ++ns) {
            const int col = gn + wn * 64 + ns * 16 + l16;
            const int row0 = gm + wm * 64 + ms * 16 + quad * 4;
            if (MODE == 1) {
#pragma unroll
                for (int r = 0; r < 4; ++r)
                    fout[(size_t)(row0 + r) * E_ + col] = acc[ms][ns][r];
            } else {
                const int h = col >> 6, d = col & (DK_ - 1);
#pragma unroll
                for (int r = 0; r < 4; ++r) {
                    const int i = row0 + r;
                    const int bb = i >> 11, s = i & (S_ - 1);
                    const float v = acc[ms][ns][r];
                    if (sel == 2)
                        vtws[(((size_t)(bb * H_ + h)) * DK_ + d) * S_ + s] = (bf16)v;
                    else if (sel == 1)
                        kws[(((size_t)(bb * H_ + h)) * S_ + s) * DK_ + d] = (bf16)v;
                    else
                        qws[(((size_t)(bb * H_ + h)) * S_ + s) * DK_ + d] = (bf16)v;
                }
            }
        }
#undef STG
#undef LDFRAGS
#undef MFMACL
}

// ---------------------------------------------------------------------------
// Flash attention (unchanged; verified, 117.8us -- next round's target).
// ---------------------------------------------------------------------------
#define PSTR 72
__global__ __launch_bounds__(256) void attn4(const bf16* __restrict__ q,
                                             const bf16* __restrict__ k,
                                             const bf16* __restrict__ vt,
                                             bf16* __restrict__ ctx) {
    __shared__ __align__(16) bf16 sK[64 * 64];
    __shared__ __align__(16) bf16 sV[64 * 64];
    __shared__ __align__(16) bf16 plds[4][32 * PSTR];

    const int t = threadIdx.x;
    const int lane = t & 63, wave = t >> 6;
    const int quad = lane >> 4, l16 = lane & 15;
    const int qb = (blockIdx.x * 4 + wave) * 32;
    const int bh = blockIdx.y;
    const size_t base  = (size_t)bh * S_ * DK_;
    const size_t baseT = (size_t)bh * DK_ * S_;
    bf16* pw = &plds[wave][0];

    const int srow = t >> 2, sc4 = (t & 3) * 16;
    const int cb = (t & 3) * 2, swr = srow & 7;
    const bf16* gK = k + base + (size_t)srow * DK_ + sc4;
    const bf16* gV = vt + baseT + (size_t)srow * S_ + sc4;
    char* wK0 = (char*)sK + srow * 128 + ((cb ^ swr) * 16);
    char* wK1 = (char*)sK + srow * 128 + (((cb + 1) ^ swr) * 16);
    char* wV0 = (char*)sV + srow * 128 + ((cb ^ swr) * 16);
    char* wV1 = (char*)sV + srow * 128 + (((cb + 1) ^ swr) * 16);

    bf16x8 rk[2], rv[2];
    rk[0] = *(const bf16x8*)(gK);
    rk[1] = *(const bf16x8*)(gK + 8);
    rv[0] = *(const bf16x8*)(gV);
    rv[1] = *(const bf16x8*)(gV + 8);

    bf16x8 aQ[2][2];
#pragma unroll
    for (int t2 = 0; t2 < 2; ++t2) {
        const bf16* qp = q + base + (size_t)(qb + t2 * 16 + l16) * DK_ + quad * 8;
        aQ[t2][0] = *(const bf16x8*)(qp);
        aQ[t2][1] = *(const bf16x8*)(qp + 32);
    }

    f32x4 acc[2][4];
    float l_i[2][4];
#pragma unroll
    for (int t2 = 0; t2 < 2; ++t2)
#pragma unroll
        for (int nb = 0; nb < 4; ++nb) {
            acc[t2][nb] = f32x4{0.f, 0.f, 0.f, 0.f};
            l_i[t2][nb] = 0.f;
        }

    for (int kt = 0; kt < S_ / 64; ++kt) {
        __syncthreads();
        *(bf16x8*)wK0 = rk[0];
        *(bf16x8*)wK1 = rk[1];
        *(bf16x8*)wV0 = rv[0];
        *(bf16x8*)wV1 = rv[1];
        __syncthreads();
        if (kt + 1 < S_ / 64) {
            const bf16* nK = gK + (size_t)(kt + 1) * 64 * DK_;
            const bf16* nV = gV + (size_t)(kt + 1) * 64;
            rk[0] = *(const bf16x8*)(nK);
            rk[1] = *(const bf16x8*)(nK + 8);
            rv[0] = *(const bf16x8*)(nV);
            rv[1] = *(const bf16x8*)(nV + 8);
        }

        f32x4 sc[2][4];
#pragma unroll
        for (int kb = 0; kb < 4; ++kb) {
            const int r = kb * 16 + l16, sw = r & 7;
            const bf16x8 b0 =
                *(const bf16x8*)((const char*)sK + r * 128 + ((quad ^ sw) * 16));
            const bf16x8 b1 = *(const bf16x8*)((const char*)sK + r * 128 +
                                               (((quad + 4) ^ sw) * 16));
#pragma unroll
            for (int t2 = 0; t2 < 2; ++t2) {
                f32x4 z = f32x4{0.f, 0.f, 0.f, 0.f};
                z = mfma16(aQ[t2][0], b0, z);
                sc[t2][kb] = mfma16(aQ[t2][1], b1, z);
            }
        }

#pragma unroll
        for (int t2 = 0; t2 < 2; ++t2)
#pragma unroll
            for (int r = 0; r < 4; ++r) {
                const int prow = (t2 * 16 + quad * 4 + r) * PSTR;
#pragma unroll
                for (int kb = 0; kb < 4; ++kb) {
                    const float p = __builtin_amdgcn_exp2f(sc[t2][kb][r]);
                    l_i[t2][r] += p;
                    pw[prow + kb * 16 + l16] = (bf16)p;
                }
            }

        bf16x8 aP[2][2];
#pragma unroll
        for (int t2 = 0; t2 < 2; ++t2) {
            aP[t2][0] = *(const bf16x8*)(pw + (t2 * 16 + l16) * PSTR + quad * 8);
            aP[t2][1] = *(const bf16x8*)(pw + (t2 * 16 + l16) * PSTR + 32 + quad * 8);
        }

#pragma unroll
        for (int nb = 0; nb < 4; ++nb) {
            const int r = nb * 16 + l16, sw = r & 7;
            const bf16x8 b0 =
                *(const bf16x8*)((const char*)sV + r * 128 + ((quad ^ sw) * 16));
            const bf16x8 b1 = *(const bf16x8*)((const char*)sV + r * 128 +
                                               (((quad + 4) ^ sw) * 16));
#pragma unroll
            for (int t2 = 0; t2 < 2; ++t2) {
                acc[t2][nb] = mfma16(aP[t2][0], b0, acc[t2][nb]);
                acc[t2][nb] = mfma16(aP[t2][1], b1, acc[t2][nb]);
            }
        }
    }

#pragma unroll
    for (int t2 = 0; t2 < 2; ++t2)
#pragma unroll
        for (int r = 0; r < 4; ++r) {
            float x = l_i[t2][r];
            x += __shfl_xor(x, 1);
            x += __shfl_xor(x, 2);
            x += __shfl_xor(x, 4);
            x += __shfl_xor(x, 8);
            l_i[t2][r] = 1.f / x;
        }

    const int b = bh >> 4, h = bh & (H_ - 1);
#pragma unroll
    for (int t2 = 0; t2 < 2; ++t2)
#pragma unroll
        for (int nb = 0; nb < 4; ++nb)
#pragma unroll
            for (int r = 0; r < 4; ++r) {
                const int s = qb + t2 * 16 + quad * 4 + r;
                const size_t idx =
                    ((size_t)(b * S_ + s)) * E_ + h * DK_ + nb * 16 + l16;
                ctx[idx] = (bf16)(acc[t2][nb][r] * l_i[t2][r]);
            }
}

// ---------------------------------------------------------------------------
extern "C" void kernel_launch(void* const* d_in, const int* in_sizes, int n_in,
                              void* d_out, int out_size, void* d_ws,
                              size_t ws_size, hipStream_t stream) {
    const float* Q  = (const float*)d_in[0];
    const float* K  = (const float*)d_in[1];
    const float* V  = (const float*)d_in[2];
    // d_in[3] = mask (unused)
    const float* Wq = (const float*)d_in[4];
    const float* Wk = (const float*)d_in[5];
    const float* Wv = (const float*)d_in[6];
    const float* Wo = (const float*)d_in[7];
    float* out = (float*)d_out;

    const size_t NTOK = (size_t)B_ * S_ * E_;  // 8,388,608
    bf16* qws  = (bf16*)d_ws;
    bf16* kws  = qws + NTOK;
    bf16* vtws = kws + NTOK;
    bf16* cws  = vtws + NTOK;  // 67.1 MB ws total (proven fits)

    // dead-phase aliases:
    //  Wq/Wk/Wv bf16 -> cws region (ctx not written until attn4)
    //  Wo bf16       -> qws region (q dead after attn4)
    //  Qb/Kb bf16    -> d_out scratch (out written only by gemmr<1>);
    //  Vb overlays Qb after the Q/K projections consumed it.
    bf16* wqkvb = cws;
    bf16* wob   = qws;
    bf16* Qb = (bf16*)d_out;
    bf16* Kb = Qb + NTOK;
    bf16* Vb = Qb;

    cvt_pair<<<dim3(4096, 2), 256, 0, stream>>>(Q, K, Qb, Kb);
    cvtw3<<<dim3(512, 3), 256, 0, stream>>>(Wq, Wk, Wv, wqkvb, CSC);

    // Q & K projections: 512 blocks = 2 full rounds
    gemmr<0><<<dim3(64, 8), 512, 0, stream>>>(
        Qb, Kb, Vb, wqkvb, qws, kws, vtws, nullptr, 0);

    cvt_pair<<<dim3(4096, 1), 256, 0, stream>>>(V, V, Vb, Vb);

    // V projection: 256 blocks = 1 full round
    gemmr<0><<<dim3(64, 4), 512, 0, stream>>>(
        Qb, Kb, Vb, wqkvb, qws, kws, vtws, nullptr, 2);

    attn4<<<dim3(S_ / 128, B_ * H_), 256, 0, stream>>>(qws, kws, vtws, cws);

    cvtw3<<<dim3(512, 1), 256, 0, stream>>>(Wo, Wo, Wo, wob, 1.f);

    // output GEMM: 256 blocks = 1 full round
    gemmr<1><<<dim3(64, 4), 512, 0, stream>>>(
        cws, cws, cws, wob, nullptr, nullptr, nullptr, out, 0);
}

// Round 7
// 339.561 us; speedup vs baseline: 1.1363x; 1.1321x over previous
//
#include <hip/hip_runtime.h>
#include <hip/hip_bf16.h>

// MultiHeadAttention: B=4 S=2048 E=1024 H=16 Dk=64
// fp32 in/out, bf16 intermediates.
#define B_  4
#define S_  2048
#define E_  1024
#define H_  16
#define DK_ 64
#define CSC 0.18033688011112042f  // log2(e)/sqrt(Dk), folded into bf16 Wq

using bf16   = __bf16;
using bf16x4 = __attribute__((ext_vector_type(4))) __bf16;
using bf16x8 = __attribute__((ext_vector_type(8))) __bf16;
using f32x4  = __attribute__((ext_vector_type(4))) float;

__device__ __forceinline__ f32x4 mfma16(bf16x8 a, bf16x8 b, f32x4 c) {
    return __builtin_amdgcn_mfma_f32_16x16x32_bf16(a, b, c, 0, 0, 0);
}

__device__ __forceinline__ bf16x8 cvt8(float4 a, float4 b) {
    bf16x8 r;
    r[0] = (bf16)a.x; r[1] = (bf16)a.y; r[2] = (bf16)a.z; r[3] = (bf16)a.w;
    r[4] = (bf16)b.x; r[5] = (bf16)b.y; r[6] = (bf16)b.z; r[7] = (bf16)b.w;
    return r;
}

// async global->LDS, 16B/lane; LDS dest = wave-uniform base + lane*16.
__device__ __forceinline__ void gl16(const void* g, void* l) {
    __builtin_amdgcn_global_load_lds(
        (const __attribute__((address_space(1))) void*)g,
        (__attribute__((address_space(3))) void*)l, 16, 0, 0);
}

#define SBAR() __builtin_amdgcn_s_barrier()
// rule #18: sched_barrier(0) after inline-asm waits so dependent ops can't hoist.
#define WV3() { asm volatile("s_waitcnt vmcnt(3)" ::: "memory");   \
                __builtin_amdgcn_sched_barrier(0); }
#define WV0() { asm volatile("s_waitcnt vmcnt(0)" ::: "memory");   \
                __builtin_amdgcn_sched_barrier(0); }
#define WL0() { asm volatile("s_waitcnt lgkmcnt(0)" ::: "memory"); \
                __builtin_amdgcn_sched_barrier(0); }

// ---------------------------------------------------------------------------
// fp32 -> bf16 streaming converts.
// ---------------------------------------------------------------------------
__global__ __launch_bounds__(256) void cvt_pair(const float* __restrict__ a,
                                                const float* __restrict__ b,
                                                bf16* __restrict__ da,
                                                bf16* __restrict__ db) {
    const float* s = blockIdx.y ? b : a;
    bf16* d = blockIdx.y ? db : da;
    const size_t i = (size_t)blockIdx.x * 256 + threadIdx.x;
    const float4 u = ((const float4*)s)[i * 2];
    const float4 v = ((const float4*)s)[i * 2 + 1];
    ((bf16x8*)d)[i] = cvt8(u, v);
}

__global__ __launch_bounds__(256) void cvtw3(const float* __restrict__ a,
                                             const float* __restrict__ b,
                                             const float* __restrict__ c,
                                             bf16* __restrict__ d, float s0) {
    const int y = blockIdx.y;
    const float* s = y == 0 ? a : y == 1 ? b : c;
    const float sc = y == 0 ? s0 : 1.f;
    const size_t i = (size_t)blockIdx.x * 256 + threadIdx.x;
    float4 u = ((const float4*)s)[i * 2];
    float4 v = ((const float4*)s)[i * 2 + 1];
    u.x *= sc; u.y *= sc; u.z *= sc; u.w *= sc;
    v.x *= sc; v.y *= sc; v.z *= sc; v.w *= sc;
    ((bf16x8*)(d + (size_t)y * E_ * E_))[i] = cvt8(u, v);
}

// ---------------------------------------------------------------------------
// 128x256 8-wave GEMM on a 3-slab LDS ring.
// vs round 6 (4-slab, 96KB, 1 block/CU): 72KB -> TWO blocks/CU so a stalled
// block no longer idles the CU (block-level TLP), lead = 2 slabs, vmcnt(3).
// Race logic: STG(s+2) writes buf (s+2)%3 = (s-1)%3, whose readers drained
// their lgkm before reaching the slab-s barrier. One barrier + one counted
// vmcnt per slab; never 0 in the main loop. Epilogue waits 3 -> 0.
// Swizzle: 64B rows, chunk' = chunk ^ ((row>>1)&3), carried by the gl16
// SOURCE address (linear LDS dest) and the ds_read address (both-sides).
// This layout measured ZERO bank conflicts (round 4).
// __launch_bounds__(512,4): VGPR cap 128, usage ~105 (acc 64 + frags 16 +
// addr). Spill tripwire: WRITE_SIZE (round-3 lesson).
// MODE 0: QKV epilogue scatter (sel = selbase + blockIdx.y>>2);
// MODE 1: fp32 linear out.
// ---------------------------------------------------------------------------
template <int MODE>
__global__ __launch_bounds__(512, 4) void gemmr(
    const bf16* __restrict__ Aq, const bf16* __restrict__ Ak,
    const bf16* __restrict__ Av, const bf16* __restrict__ Wb,
    bf16* __restrict__ qws, bf16* __restrict__ kws, bf16* __restrict__ vtws,
    float* __restrict__ fout, int selbase) {
    __shared__ __align__(16) char sm[3 * 24576];  // 72 KB

    const int t = threadIdx.x;
    const int lane = t & 63, w = t >> 6;
    const int wm = w >> 2, wn = w & 3;  // 2M x 4N
    const int quad = lane >> 4, l16 = lane & 15;

    int sel, gn;
    if (MODE == 0) {
        sel = selbase + (blockIdx.y >> 2);
        gn = (blockIdx.y & 3) * 256;
    } else {
        sel = 0;
        gn = blockIdx.y * 256;
    }
    const int gm = blockIdx.x * 128;

    const bf16* A = (MODE == 1) ? Aq : (sel == 0 ? Aq : sel == 1 ? Ak : Av);
    const bf16* W = (MODE == 1) ? Wb : Wb + (size_t)sel * E_ * E_;

    // ---- staging geometry: lane covers row l>>2, chunk l&3 (pre-swizzled)
    const int srow = lane >> 2;
    const int scw  = (lane & 3) ^ ((lane >> 3) & 3);  // ((row>>1)&3) == (l>>3)&3
    const char* gA  = (const char*)(A + (size_t)(gm + w * 16 + srow) * E_) + scw * 16;
    const char* gB0 = (const char*)(W + (size_t)(gn + w * 32 + srow) * E_) + scw * 16;
    const char* gB1 = gB0 + (size_t)16 * E_ * 2;

#define STG(bb, s) {                                                   \
        const size_t _k = (size_t)(s) * 64; /* 32 bf16 = 64B */        \
        gl16(gA + _k, sm + (bb) + w * 1024);                           \
        gl16(gB0 + _k, sm + (bb) + 8192 + w * 2048);                   \
        gl16(gB1 + _k, sm + (bb) + 8192 + w * 2048 + 1024);            \
    }

    bf16x8 Af[4], Bf[4];
#define LDFRAGS(bb) {                                                  \
        _Pragma("unroll") for (int ms = 0; ms < 4; ++ms) {             \
            const int r = wm * 64 + ms * 16 + l16;                     \
            Af[ms] = *(const bf16x8*)(sm + (bb) + r * 64 +             \
                                      ((quad ^ ((r >> 1) & 3)) * 16)); \
        }                                                              \
        _Pragma("unroll") for (int ns = 0; ns < 4; ++ns) {             \
            const int r = wn * 64 + ns * 16 + l16;                     \
            Bf[ns] = *(const bf16x8*)(sm + (bb) + 8192 + r * 64 +      \
                                      ((quad ^ ((r >> 1) & 3)) * 16)); \
        }                                                              \
    }

#define MFMACL() {                                                     \
        __builtin_amdgcn_s_setprio(1);                                 \
        _Pragma("unroll") for (int ms = 0; ms < 4; ++ms)               \
        _Pragma("unroll") for (int ns = 0; ns < 4; ++ns)               \
            acc[ms][ns] = mfma16(Af[ms], Bf[ns], acc[ms][ns]);         \
        __builtin_amdgcn_s_setprio(0);                                 \
    }

    f32x4 acc[4][4];
#pragma unroll
    for (int i = 0; i < 4; ++i)
#pragma unroll
        for (int j = 0; j < 4; ++j) acc[i][j] = f32x4{0.f, 0.f, 0.f, 0.f};

    // ---- prologue: stage slabs 0,1 (6 loads in flight)
    STG(0, 0); STG(24576, 1);

    // ---- main loop: slabs 0..29, stage s+2, one barrier + one vmcnt(3) each
    int bc = 0, bs = 2 * 24576;
    for (int s = 0; s < 30; ++s) {
        WV3();          // slab s's 3 loads landed (s+1's may be in flight)
        SBAR();         // collective; closes slab s-1's reads
        STG(bs, s + 2); // into buf (s-1)%3 -- no readers
        LDFRAGS(bc);
        WL0();
        MFMACL();
        bc += 24576; if (bc == 73728) bc = 0;
        bs += 24576; if (bs == 73728) bs = 0;
    }
    // ---- epilogue slabs 30,31: waits 3 -> 0, no staging
    WV3(); SBAR(); LDFRAGS(bc); WL0(); MFMACL();
    bc += 24576; if (bc == 73728) bc = 0;
    WV0(); SBAR(); LDFRAGS(bc); WL0(); MFMACL();

    // ---- epilogue: C/D col = lane&15, row = quad*4 + reg [HW-verified]
#pragma unroll
    for (int ms = 0; ms < 4; ++ms)
#pragma unroll
        for (int ns = 0; ns < 4; ++ns) {
            const int col = gn + wn * 64 + ns * 16 + l16;
            const int row0 = gm + wm * 64 + ms * 16 + quad * 4;
            if (MODE == 1) {
#pragma unroll
                for (int r = 0; r < 4; ++r)
                    fout[(size_t)(row0 + r) * E_ + col] = acc[ms][ns][r];
            } else {
                const int h = col >> 6, d = col & (DK_ - 1);
#pragma unroll
                for (int r = 0; r < 4; ++r) {
                    const int i = row0 + r;
                    const int bb = i >> 11, s = i & (S_ - 1);
                    const float v = acc[ms][ns][r];
                    if (sel == 2)
                        vtws[(((size_t)(bb * H_ + h)) * DK_ + d) * S_ + s] = (bf16)v;
                    else if (sel == 1)
                        kws[(((size_t)(bb * H_ + h)) * S_ + s) * DK_ + d] = (bf16)v;
                    else
                        qws[(((size_t)(bb * H_ + h)) * S_ + s) * DK_ + d] = (bf16)v;
                }
            }
        }
#undef STG
#undef LDFRAGS
#undef MFMACL
}

// ---------------------------------------------------------------------------
// Flash attention with SWAPPED QK^T (T12 idea): compute S^T = mfma(K, Q) so
// each lane owns a P ROW (q = l16) instead of a column. The P roundtrip
// becomes 8x ds_write_b64 + 4x ds_read_b128 per tile (was 32 scalar
// ds_write_b16 + 4 reads), and the row-sum is lane-local (reduce once at
// the end via shfl_xor 16/32). Per-wave P buffer [32 q][64 key] bf16,
// 128B rows, XOR-16B-chunk swizzle (chunk ^ (row&7)) on write AND read:
// reads conflict-free, writes 2-way (free per m136).
// Verified mappings:
//  S^T frag: scT[t2][kb][r] = S[q=qb+t2*16+l16][key=kt*64+kb*16+quad*4+r]
//  write (t2,kb): 4 keys quad*4+{0..3} +16kb -> one b64 at chunk 2kb+(quad>>1),
//    half (quad&1), row t2*16+l16
//  read aP[t2][h]: P[q][key=32h+quad*8+j] -> b128 at chunk 4h+quad, same row
//  PV (A=aP m=q, B=sV n=d) -> acc rows q=quad*4+r, cols d=l16+16nb: epilogue
//    mapping IDENTICAL to previous verified kernel.
// ---------------------------------------------------------------------------
__global__ __launch_bounds__(256) void attn4(const bf16* __restrict__ q,
                                             const bf16* __restrict__ k,
                                             const bf16* __restrict__ vt,
                                             bf16* __restrict__ ctx) {
    __shared__ __align__(16) bf16 sK[64 * 64];      // [key][dk], swizzled
    __shared__ __align__(16) bf16 sV[64 * 64];      // [dk][key], swizzled
    __shared__ __align__(16) bf16 pP[4][32 * 64];   // per-wave P [q][key], swz

    const int t = threadIdx.x;
    const int lane = t & 63, wave = t >> 6;
    const int quad = lane >> 4, l16 = lane & 15;
    const int qb = (blockIdx.x * 4 + wave) * 32;
    const int bh = blockIdx.y;
    const size_t base  = (size_t)bh * S_ * DK_;
    const size_t baseT = (size_t)bh * DK_ * S_;
    char* pwb = (char*)&pP[wave][0];

    const int srow = t >> 2, sc4 = (t & 3) * 16;
    const int cb = (t & 3) * 2, swr = srow & 7;
    const bf16* gK = k + base + (size_t)srow * DK_ + sc4;
    const bf16* gV = vt + baseT + (size_t)srow * S_ + sc4;
    char* wK0 = (char*)sK + srow * 128 + ((cb ^ swr) * 16);
    char* wK1 = (char*)sK + srow * 128 + (((cb + 1) ^ swr) * 16);
    char* wV0 = (char*)sV + srow * 128 + ((cb ^ swr) * 16);
    char* wV1 = (char*)sV + srow * 128 + (((cb + 1) ^ swr) * 16);

    bf16x8 rk[2], rv[2];
    rk[0] = *(const bf16x8*)(gK);
    rk[1] = *(const bf16x8*)(gK + 8);
    rv[0] = *(const bf16x8*)(gV);
    rv[1] = *(const bf16x8*)(gV + 8);

    // Q fragments (pre-scaled by CSC): Q[q=qb+t2*16+l16][dk=quad*8+j]
    bf16x8 aQ[2][2];
#pragma unroll
    for (int t2 = 0; t2 < 2; ++t2) {
        const bf16* qp = q + base + (size_t)(qb + t2 * 16 + l16) * DK_ + quad * 8;
        aQ[t2][0] = *(const bf16x8*)(qp);
        aQ[t2][1] = *(const bf16x8*)(qp + 32);
    }

    f32x4 acc[2][4];
    float l_i[2] = {0.f, 0.f};
#pragma unroll
    for (int t2 = 0; t2 < 2; ++t2)
#pragma unroll
        for (int nb = 0; nb < 4; ++nb) acc[t2][nb] = f32x4{0.f, 0.f, 0.f, 0.f};

    for (int kt = 0; kt < S_ / 64; ++kt) {
        __syncthreads();
        *(bf16x8*)wK0 = rk[0];
        *(bf16x8*)wK1 = rk[1];
        *(bf16x8*)wV0 = rv[0];
        *(bf16x8*)wV1 = rv[1];
        __syncthreads();
        if (kt + 1 < S_ / 64) {
            const bf16* nK = gK + (size_t)(kt + 1) * 64 * DK_;
            const bf16* nV = gV + (size_t)(kt + 1) * 64;
            rk[0] = *(const bf16x8*)(nK);
            rk[1] = *(const bf16x8*)(nK + 8);
            rv[0] = *(const bf16x8*)(nV);
            rv[1] = *(const bf16x8*)(nV + 8);
        }

        // ---- QK^T SWAPPED: A = K-frag (m=key), B = Q-frag (n=q)
        f32x4 scT[2][4];
#pragma unroll
        for (int kb = 0; kb < 4; ++kb) {
            const int r = kb * 16 + l16, sw = r & 7;
            const bf16x8 b0 =
                *(const bf16x8*)((const char*)sK + r * 128 + ((quad ^ sw) * 16));
            const bf16x8 b1 = *(const bf16x8*)((const char*)sK + r * 128 +
                                               (((quad + 4) ^ sw) * 16));
#pragma unroll
            for (int t2 = 0; t2 < 2; ++t2) {
                f32x4 z = f32x4{0.f, 0.f, 0.f, 0.f};
                z = mfma16(b0, aQ[t2][0], z);
                scT[t2][kb] = mfma16(b1, aQ[t2][1], z);
            }
        }

        // ---- flat exp, lane-local row-sum, packed b64 P-writes
#pragma unroll
        for (int t2 = 0; t2 < 2; ++t2) {
            const int prow = (t2 * 16 + l16) * 128;
#pragma unroll
            for (int kb = 0; kb < 4; ++kb) {
                const float p0 = __builtin_amdgcn_exp2f(scT[t2][kb][0]);
                const float p1 = __builtin_amdgcn_exp2f(scT[t2][kb][1]);
                const float p2 = __builtin_amdgcn_exp2f(scT[t2][kb][2]);
                const float p3 = __builtin_amdgcn_exp2f(scT[t2][kb][3]);
                l_i[t2] += (p0 + p1) + (p2 + p3);
                bf16x4 pv;
                pv[0] = (bf16)p0; pv[1] = (bf16)p1;
                pv[2] = (bf16)p2; pv[3] = (bf16)p3;
                *(bf16x4*)(pwb + prow +
                           (((2 * kb + (quad >> 1)) ^ (l16 & 7)) * 16) +
                           (quad & 1) * 8) = pv;
            }
        }

        // ---- P as A-operand: vector b128 reads (swizzled)
        bf16x8 aP[2][2];
#pragma unroll
        for (int t2 = 0; t2 < 2; ++t2) {
            const int prow = (t2 * 16 + l16) * 128;
            aP[t2][0] = *(const bf16x8*)(pwb + prow + (((quad) ^ (l16 & 7)) * 16));
            aP[t2][1] =
                *(const bf16x8*)(pwb + prow + (((4 + quad) ^ (l16 & 7)) * 16));
        }

        // ---- PV from sV: B[k=key][n=d], swizzled read (unchanged)
#pragma unroll
        for (int nb = 0; nb < 4; ++nb) {
            const int r = nb * 16 + l16, sw = r & 7;
            const bf16x8 b0 =
                *(const bf16x8*)((const char*)sV + r * 128 + ((quad ^ sw) * 16));
            const bf16x8 b1 = *(const bf16x8*)((const char*)sV + r * 128 +
                                               (((quad + 4) ^ sw) * 16));
#pragma unroll
            for (int t2 = 0; t2 < 2; ++t2) {
                acc[t2][nb] = mfma16(aP[t2][0], b0, acc[t2][nb]);
                acc[t2][nb] = mfma16(aP[t2][1], b1, acc[t2][nb]);
            }
        }
    }

    // ---- reduce lane-local sums across the 4 quad-copies of q=l16
    float linv[2];
#pragma unroll
    for (int t2 = 0; t2 < 2; ++t2) {
        float x = l_i[t2];
        x += __shfl_xor(x, 16);
        x += __shfl_xor(x, 32);
        linv[t2] = 1.f / x;
    }

    const int b = bh >> 4, h = bh & (H_ - 1);
#pragma unroll
    for (int t2 = 0; t2 < 2; ++t2)
#pragma unroll
        for (int r = 0; r < 4; ++r) {
            // acc rows hold q = quad*4 + r; lane quad*4+r (of lanes 0-15)
            // holds 1/l for that q after the xor-reduce.
            const float li = __shfl(linv[t2], quad * 4 + r);
            const int s = qb + t2 * 16 + quad * 4 + r;
#pragma unroll
            for (int nb = 0; nb < 4; ++nb) {
                const size_t idx =
                    ((size_t)(b * S_ + s)) * E_ + h * DK_ + nb * 16 + l16;
                ctx[idx] = (bf16)(acc[t2][nb][r] * li);
            }
        }
}

// ---------------------------------------------------------------------------
extern "C" void kernel_launch(void* const* d_in, const int* in_sizes, int n_in,
                              void* d_out, int out_size, void* d_ws,
                              size_t ws_size, hipStream_t stream) {
    const float* Q  = (const float*)d_in[0];
    const float* K  = (const float*)d_in[1];
    const float* V  = (const float*)d_in[2];
    // d_in[3] = mask (unused)
    const float* Wq = (const float*)d_in[4];
    const float* Wk = (const float*)d_in[5];
    const float* Wv = (const float*)d_in[6];
    const float* Wo = (const float*)d_in[7];
    float* out = (float*)d_out;

    const size_t NTOK = (size_t)B_ * S_ * E_;  // 8,388,608
    bf16* qws  = (bf16*)d_ws;
    bf16* kws  = qws + NTOK;
    bf16* vtws = kws + NTOK;
    bf16* cws  = vtws + NTOK;  // 67.1 MB ws total (proven fits)

    // dead-phase aliases:
    //  Wq/Wk/Wv bf16 -> cws region (ctx not written until attn4)
    //  Wo bf16       -> qws region (q dead after attn4)
    //  Qb/Kb bf16    -> d_out scratch (out written only by gemmr<1>);
    //  Vb overlays Qb after the Q/K projections consumed it.
    bf16* wqkvb = cws;
    bf16* wob   = qws;
    bf16* Qb = (bf16*)d_out;
    bf16* Kb = Qb + NTOK;
    bf16* Vb = Qb;

    cvt_pair<<<dim3(4096, 2), 256, 0, stream>>>(Q, K, Qb, Kb);
    cvtw3<<<dim3(512, 3), 256, 0, stream>>>(Wq, Wk, Wv, wqkvb, CSC);

    // Q & K projections: 512 blocks = 2/CU resident (72KB LDS x2 fits)
    gemmr<0><<<dim3(64, 8), 512, 0, stream>>>(
        Qb, Kb, Vb, wqkvb, qws, kws, vtws, nullptr, 0);

    cvt_pair<<<dim3(4096, 1), 256, 0, stream>>>(V, V, Vb, Vb);

    // V projection: 256 blocks
    gemmr<0><<<dim3(64, 4), 512, 0, stream>>>(
        Qb, Kb, Vb, wqkvb, qws, kws, vtws, nullptr, 2);

    attn4<<<dim3(S_ / 128, B_ * H_), 256, 0, stream>>>(qws, kws, vtws, cws);

    cvtw3<<<dim3(512, 1), 256, 0, stream>>>(Wo, Wo, Wo, wob, 1.f);

    // output GEMM: 256 blocks
    gemmr<1><<<dim3(64, 4), 512, 0, stream>>>(
        cws, cws, cws, wob, nullptr, nullptr, nullptr, out, 0);
}